// Round 7
// baseline (8380.872 us; speedup 1.0000x reference)
//
#include <hip/hip_runtime.h>
#include <hip/hip_bf16.h>

#define S 2048
#define HD 512
#define EDIM 512
#define NT 12
#define G4 2048            // 4*HD gate rows
#define WGD 32             // workgroups per direction (= CUs of one XCD)
#define UPW 16             // hidden units per WG

typedef unsigned short ushort_t;
typedef unsigned int uint_t;
typedef unsigned int u32x4 __attribute__((ext_vector_type(4)));

__device__ __forceinline__ ushort_t f2b(float f) {
    uint_t u = __float_as_uint(f);
    uint_t r = u + 0x7fffu + ((u >> 16) & 1u);
    return (ushort_t)(r >> 16);
}
__device__ __forceinline__ float b2f(ushort_t h) {
    return __uint_as_float(((uint_t)h) << 16);
}
__device__ __forceinline__ float sigm(float x) { return 1.f / (1.f + __expf(-x)); }
__device__ __forceinline__ float tanh_(float x) {
    float e = __expf(2.f * x);
    return 1.f - 2.f / (e + 1.f);
}

// L1-bypass load (intended: served by same-XCD L2). If sc0 semantics differ on
// gfx950, callers MUST pair this with a periodic agent-scope fallback load.
__device__ __forceinline__ u32x4 load_sc0(const void* p) {
    u32x4 v;
    asm volatile("global_load_dwordx4 %0, %1, off sc0" : "=v"(v) : "v"(p) : "memory");
    asm volatile("s_waitcnt vmcnt(0)" ::: "memory");
    return v;
}

// ---------------- xw GEMM: xwT[d][r][t] = emb[tok(d,t)] . wih_d[r] + b_d[r] (TRANSPOSED out) ----
__global__ __launch_bounds__(256, 2)
void xw_gemm(const int* __restrict__ sentence, const float* __restrict__ emb,
             const float* __restrict__ wih_f, const float* __restrict__ b_f,
             const float* __restrict__ wih_b, const float* __restrict__ b_b,
             ushort_t* __restrict__ xwT) {
    __shared__ float As[32][68];
    __shared__ float Bs[32][68];
    __shared__ int toks[64];
    const int tid = threadIdx.x;
    const int tbase = blockIdx.x * 64;
    const int rbase = blockIdx.y * 64;
    const int dir = blockIdx.z;
    const float* wih = dir ? wih_b : wih_f;
    const float* bia = dir ? b_b : b_f;
    if (tid < 64) {
        int tt = tbase + tid;
        toks[tid] = sentence[dir ? (S - 1 - tt) : tt];
    }
    __syncthreads();
    const int lm = tid >> 2;
    const int lk = (tid & 3) * 8;
    const int ty = tid >> 4, tx = tid & 15;
    const float* aBase = emb + (size_t)toks[lm] * EDIM + lk;
    const float* bBase = wih + (size_t)(rbase + lm) * EDIM + lk;
    float acc[4][4];
#pragma unroll
    for (int i = 0; i < 4; ++i)
#pragma unroll
        for (int j = 0; j < 4; ++j) acc[i][j] = 0.f;

    for (int kcc = 0; kcc < EDIM; kcc += 32) {
        float4 a0 = ((const float4*)(aBase + kcc))[0];
        float4 a1 = ((const float4*)(aBase + kcc))[1];
        float4 b0 = ((const float4*)(bBase + kcc))[0];
        float4 b1 = ((const float4*)(bBase + kcc))[1];
        __syncthreads();
        As[lk + 0][lm] = a0.x; As[lk + 1][lm] = a0.y; As[lk + 2][lm] = a0.z; As[lk + 3][lm] = a0.w;
        As[lk + 4][lm] = a1.x; As[lk + 5][lm] = a1.y; As[lk + 6][lm] = a1.z; As[lk + 7][lm] = a1.w;
        Bs[lk + 0][lm] = b0.x; Bs[lk + 1][lm] = b0.y; Bs[lk + 2][lm] = b0.z; Bs[lk + 3][lm] = b0.w;
        Bs[lk + 4][lm] = b1.x; Bs[lk + 5][lm] = b1.y; Bs[lk + 6][lm] = b1.z; Bs[lk + 7][lm] = b1.w;
        __syncthreads();
#pragma unroll
        for (int kk = 0; kk < 32; ++kk) {
            float4 a4 = *(const float4*)&As[kk][ty * 4];
            float4 b4 = *(const float4*)&Bs[kk][tx * 4];
            float av[4] = {a4.x, a4.y, a4.z, a4.w};
            float bv[4] = {b4.x, b4.y, b4.z, b4.w};
#pragma unroll
            for (int i = 0; i < 4; ++i)
#pragma unroll
                for (int j = 0; j < 4; ++j) acc[i][j] = fmaf(av[i], bv[j], acc[i][j]);
        }
    }
    float4 bi = *(const float4*)&bia[rbase + tx * 4];
    float bvv[4] = {bi.x, bi.y, bi.z, bi.w};
#pragma unroll
    for (int j = 0; j < 4; ++j) {
        ushort4 o;
        o.x = f2b(acc[0][j] + bvv[j]);
        o.y = f2b(acc[1][j] + bvv[j]);
        o.z = f2b(acc[2][j] + bvv[j]);
        o.w = f2b(acc[3][j] + bvv[j]);
        ushort_t* p = xwT + ((size_t)dir * G4 + rbase + tx * 4 + j) * S + tbase + ty * 4;
        *(ushort4*)p = o;
    }
}

// ---------------- LSTM recurrence: XCD-pinned, L2-biased exchange with agent fallback ------
// 1024 blocks; block reads HW_REG_XCC_ID [measured m09]. XCD0->dir0, XCD1->dir1: 32 slots
// claimed via atomic; others exit. 96KB dyn LDS => 1 WG/CU => the first 32 runners per XCD sit
// on 32 distinct CUs => all claimants co-resident (deadlock-free). Producer: agent-scope atomic
// store (R2-proven, always reaches coherence point). Consumer: sc0 poll (fast, L2) with every-
// 8th-iteration agent-scope load (R2-proven) => no stale-spin hang possible.
__global__ __launch_bounds__(256, 1)
void lstm_rec(const float* __restrict__ whh_f, const float* __restrict__ whh_b,
              const float* __restrict__ h0, const float* __restrict__ c0,
              const ushort_t* __restrict__ xwT, float* hs, int* claim) {
    extern __shared__ float dynlds[];
    float* hst = dynlds;                          // 2 bufs x 16 chunks x 36 dwords = 1152 f
    ushort_t* xst = (ushort_t*)(dynlds + 1152);   // 2 bufs x 64 rows x 72 ushorts

    uint_t xcc;
    asm volatile("s_getreg_b32 %0, hwreg(HW_REG_XCC_ID)" : "=s"(xcc));
    __shared__ int slot_sh;
    if (threadIdx.x == 0)
        slot_sh = (xcc < 2) ? atomicAdd(&claim[xcc], 1) : -1;
    __syncthreads();
    const int slot = slot_sh;
    if (xcc >= 2 || slot >= WGD) return;
    const int dir = (int)xcc;

    const int tid = threadIdx.x;
    const int u = tid >> 4;                       // unit 0..15
    const int kc = tid & 15;                      // k-chunk 0..15
    const int jbase = slot * UPW;
    const float* whh = dir ? whh_b : whh_f;

    // register-stationary weights: 4 gates x 32 k = 128 f32
    float4 w[4][8];
#pragma unroll
    for (int g = 0; g < 4; ++g)
#pragma unroll
        for (int i = 0; i < 8; ++i)
            w[g][i] = *(const float4*)&whh[(size_t)(g * HD + jbase + u) * HD + kc * 32 + i * 4];

    const ushort_t* xwd = xwT + (size_t)dir * G4 * S;
    float* hsd = hs + (size_t)dir * S * HD;

    // xw chunk 0 preload: local row lr = g*16+u <-> global row g*HD + jbase + (lr&15)
    {
        int lr = tid >> 2, q = tid & 3;
        const ushort_t* src = xwd + (size_t)((lr >> 4) * HD + jbase + (lr & 15)) * S + q * 16;
        *(uint4*)&xst[lr * 72 + q * 16] = *(const uint4*)src;
        *(uint4*)&xst[lr * 72 + q * 16 + 8] = *(const uint4*)(src + 8);
    }

    const bool upd = (kc == 0);
    float cj = upd ? c0[dir * HD + jbase + u] : 0.f;

    // stage h0 into buf 1 (step t reads buf (t+1)&1)
    if (tid < 128) {
        int j = tid * 4;
        *(float4*)&hst[576 + (j >> 5) * 36 + (j & 31)] = *(const float4*)&h0[dir * HD + j];
    }
    __syncthreads();

    for (int t = 0; t < S; ++t) {
        if ((t & 63) == 0 && t + 64 < S) {        // prefetch next xw chunk
            int nb = ((t >> 6) + 1) & 1;
            int lr = tid >> 2, q = tid & 3;
            const ushort_t* src =
                xwd + (size_t)((lr >> 4) * HD + jbase + (lr & 15)) * S + (t + 64) + q * 16;
            *(uint4*)&xst[nb * 4608 + lr * 72 + q * 16] = *(const uint4*)src;
            *(uint4*)&xst[nb * 4608 + lr * 72 + q * 16 + 8] = *(const uint4*)(src + 8);
        }
        const float* hb = &hst[((t + 1) & 1) * 576];
        float4 a0 = {0, 0, 0, 0}, a1 = {0, 0, 0, 0}, a2 = {0, 0, 0, 0}, a3 = {0, 0, 0, 0};
#pragma unroll
        for (int i = 0; i < 8; ++i) {
            float4 h4 = *(const float4*)&hb[kc * 36 + i * 4];
            a0.x = fmaf(w[0][i].x, h4.x, a0.x); a0.y = fmaf(w[0][i].y, h4.y, a0.y);
            a0.z = fmaf(w[0][i].z, h4.z, a0.z); a0.w = fmaf(w[0][i].w, h4.w, a0.w);
            a1.x = fmaf(w[1][i].x, h4.x, a1.x); a1.y = fmaf(w[1][i].y, h4.y, a1.y);
            a1.z = fmaf(w[1][i].z, h4.z, a1.z); a1.w = fmaf(w[1][i].w, h4.w, a1.w);
            a2.x = fmaf(w[2][i].x, h4.x, a2.x); a2.y = fmaf(w[2][i].y, h4.y, a2.y);
            a2.z = fmaf(w[2][i].z, h4.z, a2.z); a2.w = fmaf(w[2][i].w, h4.w, a2.w);
            a3.x = fmaf(w[3][i].x, h4.x, a3.x); a3.y = fmaf(w[3][i].y, h4.y, a3.y);
            a3.z = fmaf(w[3][i].z, h4.z, a3.z); a3.w = fmaf(w[3][i].w, h4.w, a3.w);
        }
        float s0 = (a0.x + a0.y) + (a0.z + a0.w);
        float s1 = (a1.x + a1.y) + (a1.z + a1.w);
        float s2 = (a2.x + a2.y) + (a2.z + a2.w);
        float s3 = (a3.x + a3.y) + (a3.z + a3.w);
#pragma unroll
        for (int m = 1; m < 16; m <<= 1) {
            s0 += __shfl_xor(s0, m);
            s1 += __shfl_xor(s1, m);
            s2 += __shfl_xor(s2, m);
            s3 += __shfl_xor(s3, m);
        }
        if (upd) {
            int xb = (t >> 6) & 1, tt = t & 63;
            float gi = s0 + b2f(xst[xb * 4608 + (0 * 16 + u) * 72 + tt]);
            float gf = s1 + b2f(xst[xb * 4608 + (1 * 16 + u) * 72 + tt]);
            float gg = s2 + b2f(xst[xb * 4608 + (2 * 16 + u) * 72 + tt]);
            float go = s3 + b2f(xst[xb * 4608 + (3 * 16 + u) * 72 + tt]);
            float ii = sigm(gi), ff = sigm(gf), gv = tanh_(gg), oo = sigm(go);
            cj = ff * cj + ii * gv;
            float hnew = oo * tanh_(cj);
            __hip_atomic_store(&hsd[(size_t)t * HD + jbase + u], hnew,
                               __ATOMIC_RELAXED, __HIP_MEMORY_SCOPE_AGENT);
        }
        if (t < S - 1 && tid < 128) {
            // poll h(t): fast sc0 path + every-8th agent-scope fallback (no-hang guarantee)
            int j = (tid >> 2) * 16 + (tid & 3) * 4;
            const float* src = &hsd[(size_t)t * HD + j];
            u32x4 v;
            int it = 0;
            for (;;) {
                if ((++it & 7) != 0) {
                    v = load_sc0(src);
                } else {
                    unsigned long long a = __hip_atomic_load(
                        (const unsigned long long*)src, __ATOMIC_RELAXED,
                        __HIP_MEMORY_SCOPE_AGENT);
                    unsigned long long b = __hip_atomic_load(
                        (const unsigned long long*)src + 1, __ATOMIC_RELAXED,
                        __HIP_MEMORY_SCOPE_AGENT);
                    v.x = (uint_t)a; v.y = (uint_t)(a >> 32);
                    v.z = (uint_t)b; v.w = (uint_t)(b >> 32);
                }
                if (v.x != 0xFFFFFFFFu && v.y != 0xFFFFFFFFu &&
                    v.z != 0xFFFFFFFFu && v.w != 0xFFFFFFFFu) break;
            }
            *(u32x4*)&hst[(t & 1) * 576 + (j >> 5) * 36 + (j & 31)] = v;
        }
        __syncthreads();
    }
}

// ---------------- feats: [S][12] = concat(hf, hb_rev) @ w_out.T + b_out ----------------
__global__ __launch_bounds__(256)
void feats_k(const float* __restrict__ hs, const float* __restrict__ w_out,
             const float* __restrict__ b_out, float* __restrict__ feats) {
    const int t = blockIdx.x, tid = threadIdx.x;
    float4 h4;
    if (tid < 128)
        h4 = *(const float4*)&hs[(size_t)t * HD + tid * 4];
    else
        h4 = *(const float4*)&hs[(size_t)S * HD + (size_t)(S - 1 - t) * HD + (tid - 128) * 4];
    float acc[NT];
#pragma unroll
    for (int tg = 0; tg < NT; ++tg) {
        float4 w4 = *(const float4*)&w_out[(size_t)tg * 1024 + tid * 4];
        acc[tg] = h4.x * w4.x + h4.y * w4.y + h4.z * w4.z + h4.w * w4.w;
    }
#pragma unroll
    for (int m = 1; m < 64; m <<= 1)
#pragma unroll
        for (int tg = 0; tg < NT; ++tg) acc[tg] += __shfl_xor(acc[tg], m);
    __shared__ float part[4][NT];
    if ((tid & 63) == 0) {
#pragma unroll
        for (int tg = 0; tg < NT; ++tg) part[tid >> 6][tg] = acc[tg];
    }
    __syncthreads();
    if (tid < NT)
        feats[(size_t)t * NT + tid] =
            part[0][tid] + part[1][tid] + part[2][tid] + part[3][tid] + b_out[tid];
}

// ---------------- CRF: forward algorithm + gold score, single block (R1-proven) ----------
__global__ __launch_bounds__(256, 1)
void crf_k(const float* __restrict__ feats, const int* __restrict__ gold,
           const float* __restrict__ trans, float* __restrict__ out) {
    extern __shared__ float sfeats[];      // S*NT floats = 96KB
    __shared__ float red[256];
    __shared__ float nprev[NT];
    __shared__ float tr[144];
    __shared__ float gold_sh;
    const int tid = threadIdx.x;
    for (int i = tid; i < S * NT / 4; i += 256)
        ((float4*)sfeats)[i] = ((const float4*)feats)[i];
    if (tid < 144) tr[tid] = trans[tid];
    __syncthreads();
    float gsum = 0.f;
    for (int t = tid; t < S; t += 256) {
        int a = gold[t];
        int b = t ? gold[t - 1] : 0;
        gsum += tr[a * NT + b] + sfeats[t * NT + a];
    }
    red[tid] = gsum;
    __syncthreads();
    for (int s = 128; s; s >>= 1) {
        if (tid < s) red[tid] += red[tid + s];
        __syncthreads();
    }
    if (tid == 0) gold_sh = red[0] + tr[1 * NT + gold[S - 1]];
    __syncthreads();
    const int i = tid >> 4, j = tid & 15;
    const bool act = (tid < 192) && (j < NT);
    float tij = act ? tr[i * NT + j] : -3e38f;
    float prev = (j == 0) ? 0.f : -1e6f;
    for (int t = 0; t < S; ++t) {
        float v = act ? (prev + tij) : -3e38f;
        float mx = v;
        mx = fmaxf(mx, __shfl_xor(mx, 1));
        mx = fmaxf(mx, __shfl_xor(mx, 2));
        mx = fmaxf(mx, __shfl_xor(mx, 4));
        mx = fmaxf(mx, __shfl_xor(mx, 8));
        float e = __expf(v - mx);
        float ss = e;
        ss += __shfl_xor(ss, 1);
        ss += __shfl_xor(ss, 2);
        ss += __shfl_xor(ss, 4);
        ss += __shfl_xor(ss, 8);
        if (tid < 192 && j == 0) nprev[i] = mx + __logf(ss) + sfeats[t * NT + i];
        __syncthreads();
        prev = nprev[j < NT ? j : 0];
        __syncthreads();
    }
    if (tid < 64) {
        float v2 = (tid < NT) ? prev + tr[1 * NT + tid] : -3e38f;
        float mx = v2;
        mx = fmaxf(mx, __shfl_xor(mx, 1));
        mx = fmaxf(mx, __shfl_xor(mx, 2));
        mx = fmaxf(mx, __shfl_xor(mx, 4));
        mx = fmaxf(mx, __shfl_xor(mx, 8));
        float e = __expf(v2 - mx);
        float ss = e;
        ss += __shfl_xor(ss, 1);
        ss += __shfl_xor(ss, 2);
        ss += __shfl_xor(ss, 4);
        ss += __shfl_xor(ss, 8);
        if (tid == 0) out[0] = (mx + __logf(ss)) - gold_sh;
    }
}

extern "C" void kernel_launch(void* const* d_in, const int* in_sizes, int n_in,
                              void* d_out, int out_size, void* d_ws, size_t ws_size,
                              hipStream_t stream) {
    const int* sentence = (const int*)d_in[0];
    const int* gold = (const int*)d_in[1];
    const float* emb = (const float*)d_in[2];
    const float* wih_f = (const float*)d_in[3];
    const float* whh_f = (const float*)d_in[4];
    const float* b_f = (const float*)d_in[5];
    const float* wih_b = (const float*)d_in[6];
    const float* whh_b = (const float*)d_in[7];
    const float* b_b = (const float*)d_in[8];
    const float* w_out = (const float*)d_in[9];
    const float* b_out = (const float*)d_in[10];
    const float* trans = (const float*)d_in[11];
    const float* h0 = (const float*)d_in[12];
    const float* c0 = (const float*)d_in[13];
    float* out = (float*)d_out;

    char* ws = (char*)d_ws;
    const size_t XW_B = (size_t)2 * S * G4 * 2;          // 16,777,216
    const size_t HS_B = (size_t)2 * S * HD * 4;          // 8,388,608
    const size_t FT_B = (size_t)S * NT * 4;              // 98,304
    ushort_t* xwT = (ushort_t*)ws;
    float* hs = (float*)(ws + XW_B);
    float* feats = (float*)(ws + XW_B + HS_B);
    int* claim = (int*)(ws + XW_B + HS_B + FT_B);

    // canary-fill h buffer; zero claim counters
    hipMemsetAsync(hs, 0xFF, HS_B, stream);
    hipMemsetAsync(claim, 0, 256, stream);

    dim3 gg(S / 64, G4 / 64, 2);
    xw_gemm<<<gg, 256, 0, stream>>>(sentence, emb, wih_f, b_f, wih_b, b_b, xwT);

    const int REC_LDS = 96 * 1024;                       // forces 1 WG/CU (claimants distinct CUs)
    hipFuncSetAttribute((const void*)lstm_rec,
                        hipFuncAttributeMaxDynamicSharedMemorySize, REC_LDS);
    lstm_rec<<<1024, 256, REC_LDS, stream>>>(whh_f, whh_b, h0, c0, xwT, hs, claim);

    feats_k<<<S, 256, 0, stream>>>(hs, w_out, b_out, feats);

    const int CRF_LDS = S * NT * 4;                      // 98,304 B
    hipFuncSetAttribute((const void*)crf_k,
                        hipFuncAttributeMaxDynamicSharedMemorySize, CRF_LDS);
    crf_k<<<1, 256, CRF_LDS, stream>>>(feats, gold, trans, out);
}

// Round 8
// 7101.411 us; speedup vs baseline: 1.1802x; 1.1802x over previous
//
#include <hip/hip_runtime.h>
#include <hip/hip_bf16.h>

#define S 2048
#define HD 512
#define EDIM 512
#define NT 12
#define G4 2048            // 4*HD gate rows
#define NWGD 64            // workgroups per direction
#define JPW 8              // hidden units per WG

typedef unsigned short ushort_t;
typedef unsigned int uint_t;

__device__ __forceinline__ ushort_t f2b(float f) {
    uint_t u = __float_as_uint(f);
    uint_t r = u + 0x7fffu + ((u >> 16) & 1u);
    return (ushort_t)(r >> 16);
}
__device__ __forceinline__ float b2f(ushort_t h) {
    return __uint_as_float(((uint_t)h) << 16);
}
__device__ __forceinline__ float sigm(float x) { return 1.f / (1.f + __expf(-x)); }
__device__ __forceinline__ float tanh_(float x) {
    float e = __expf(2.f * x);
    return 1.f - 2.f / (e + 1.f);
}

// ---------------- xw GEMM: xwT[d][r][t] = emb[tok(d,t)] . wih_d[r] + b_d[r] (TRANSPOSED out) ----
__global__ __launch_bounds__(256, 2)
void xw_gemm(const int* __restrict__ sentence, const float* __restrict__ emb,
             const float* __restrict__ wih_f, const float* __restrict__ b_f,
             const float* __restrict__ wih_b, const float* __restrict__ b_b,
             ushort_t* __restrict__ xwT) {
    __shared__ float As[32][68];
    __shared__ float Bs[32][68];
    __shared__ int toks[64];
    const int tid = threadIdx.x;
    const int tbase = blockIdx.x * 64;
    const int rbase = blockIdx.y * 64;
    const int dir = blockIdx.z;
    const float* wih = dir ? wih_b : wih_f;
    const float* bia = dir ? b_b : b_f;
    if (tid < 64) {
        int tt = tbase + tid;
        toks[tid] = sentence[dir ? (S - 1 - tt) : tt];
    }
    __syncthreads();
    const int lm = tid >> 2;
    const int lk = (tid & 3) * 8;
    const int ty = tid >> 4, tx = tid & 15;
    const float* aBase = emb + (size_t)toks[lm] * EDIM + lk;
    const float* bBase = wih + (size_t)(rbase + lm) * EDIM + lk;
    float acc[4][4];
#pragma unroll
    for (int i = 0; i < 4; ++i)
#pragma unroll
        for (int j = 0; j < 4; ++j) acc[i][j] = 0.f;

    for (int kcc = 0; kcc < EDIM; kcc += 32) {
        float4 a0 = ((const float4*)(aBase + kcc))[0];
        float4 a1 = ((const float4*)(aBase + kcc))[1];
        float4 b0 = ((const float4*)(bBase + kcc))[0];
        float4 b1 = ((const float4*)(bBase + kcc))[1];
        __syncthreads();
        As[lk + 0][lm] = a0.x; As[lk + 1][lm] = a0.y; As[lk + 2][lm] = a0.z; As[lk + 3][lm] = a0.w;
        As[lk + 4][lm] = a1.x; As[lk + 5][lm] = a1.y; As[lk + 6][lm] = a1.z; As[lk + 7][lm] = a1.w;
        Bs[lk + 0][lm] = b0.x; Bs[lk + 1][lm] = b0.y; Bs[lk + 2][lm] = b0.z; Bs[lk + 3][lm] = b0.w;
        Bs[lk + 4][lm] = b1.x; Bs[lk + 5][lm] = b1.y; Bs[lk + 6][lm] = b1.z; Bs[lk + 7][lm] = b1.w;
        __syncthreads();
#pragma unroll
        for (int kk = 0; kk < 32; ++kk) {
            float4 a4 = *(const float4*)&As[kk][ty * 4];
            float4 b4 = *(const float4*)&Bs[kk][tx * 4];
            float av[4] = {a4.x, a4.y, a4.z, a4.w};
            float bv[4] = {b4.x, b4.y, b4.z, b4.w};
#pragma unroll
            for (int i = 0; i < 4; ++i)
#pragma unroll
                for (int j = 0; j < 4; ++j) acc[i][j] = fmaf(av[i], bv[j], acc[i][j]);
        }
    }
    float4 bi = *(const float4*)&bia[rbase + tx * 4];
    float bvv[4] = {bi.x, bi.y, bi.z, bi.w};
#pragma unroll
    for (int j = 0; j < 4; ++j) {
        ushort4 o;
        o.x = f2b(acc[0][j] + bvv[j]);
        o.y = f2b(acc[1][j] + bvv[j]);
        o.z = f2b(acc[2][j] + bvv[j]);
        o.w = f2b(acc[3][j] + bvv[j]);
        ushort_t* p = xwT + ((size_t)dir * G4 + rbase + tx * 4 + j) * S + tbase + ty * 4;
        *(ushort4*)p = o;
    }
}

// ---------------- LSTM recurrence: R2-tuned — in-wave gates, 1 barrier/step, LDS xw --------
// 128 WGs x 256 thr. Lane: rg=tid>>4 (16 row-pairs), kc=tid&15 (32-float k-chunk).
// Local row r = u*4+g (unit-major!) so unit u's 4 gate sums live in one wave:
//   rows 4u,4u+1 -> rg=2u (s0,s1); rows 4u+2,4u+3 -> rg=2u+1 -> shfl_down 16.
// Weights f32 reg-stationary. h double-buffered LDS. xw 64-step dbuf LDS chunks.
// Publish: agent-scope atomic store (proven). Poll: direct value-canary agent loads (proven).
__global__ __launch_bounds__(256, 1)
void lstm_rec(const float* __restrict__ whh_f, const float* __restrict__ whh_b,
              const float* __restrict__ h0, const float* __restrict__ c0,
              const ushort_t* __restrict__ xwT, float* hs) {
    __shared__ float hstage[2][576];            // 16 chunks x 36 dwords, padded (conflict-free)
    __shared__ ushort_t xst[2][32 * 72];        // dbuf: 32 rows x 64 steps, padded stride 72
    const int tid = threadIdx.x;
    const int dir = blockIdx.x >> 6;
    const int wg = blockIdx.x & 63;
    const int jbase = wg * JPW;
    const int rg = tid >> 4, kc = tid & 15;
    const float* whh = dir ? whh_b : whh_f;

    // rows r0=2rg, r1=2rg+1; r=u*4+g -> u=r>>2, g=r&3; grow = g*HD + jbase + u
    int grow[2];
#pragma unroll
    for (int ri = 0; ri < 2; ++ri) {
        int r = rg * 2 + ri;
        grow[ri] = (r & 3) * HD + jbase + (r >> 2);
    }
    float4 w[2][8];
#pragma unroll
    for (int ri = 0; ri < 2; ++ri)
#pragma unroll
        for (int i = 0; i < 8; ++i)
            w[ri][i] = *(const float4*)&whh[(size_t)grow[ri] * HD + kc * 32 + i * 4];

    const ushort_t* xwd = xwT + (size_t)dir * G4 * S;
    float* hsd = hs + (size_t)dir * S * HD;

    // xw chunk 0: local row lr = g*8+u  -> global row g*HD + jbase + u ; 8 lanes x 16B
    const int lr = tid >> 3, q = tid & 7;
    const ushort_t* sbase = xwd + (size_t)((lr >> 3) * HD + jbase + (lr & 7)) * S;
    *(uint4*)&xst[0][lr * 72 + q * 8] = *(const uint4*)(sbase + q * 8);

    const bool upd = (tid & 31) == 0;           // rg even, kc==0
    const int u = tid >> 5;                     // unit 0..7 (on upd lanes)
    float cj = upd ? c0[dir * HD + jbase + u] : 0.f;

    // stage h0 into buf 1 (step 0 reads buf (0+1)&1 = 1)
    {
        int p = 2 * tid;
        float2 v = *(const float2*)&h0[dir * HD + p];
        *(float2*)&hstage[1][(p >> 5) * 36 + (p & 31)] = v;
    }
    __syncthreads();

    for (int t = 0; t < S; ++t) {
        if ((t & 63) == 0 && t + 64 < S) {      // prefetch next xw chunk into other buffer
            int nb = ((t >> 6) + 1) & 1;
            *(uint4*)&xst[nb][lr * 72 + q * 8] = *(const uint4*)(sbase + (t + 64) + q * 8);
        }
        const float* hb = &hstage[(t + 1) & 1][kc * 36];
        float4 a0 = {0, 0, 0, 0}, a1 = {0, 0, 0, 0};
#pragma unroll
        for (int i = 0; i < 8; ++i) {
            float4 h4 = *(const float4*)&hb[i * 4];
            a0.x = fmaf(w[0][i].x, h4.x, a0.x); a0.y = fmaf(w[0][i].y, h4.y, a0.y);
            a0.z = fmaf(w[0][i].z, h4.z, a0.z); a0.w = fmaf(w[0][i].w, h4.w, a0.w);
            a1.x = fmaf(w[1][i].x, h4.x, a1.x); a1.y = fmaf(w[1][i].y, h4.y, a1.y);
            a1.z = fmaf(w[1][i].z, h4.z, a1.z); a1.w = fmaf(w[1][i].w, h4.w, a1.w);
        }
        float s0 = (a0.x + a0.y) + (a0.z + a0.w);
        float s1 = (a1.x + a1.y) + (a1.z + a1.w);
#pragma unroll
        for (int m = 1; m < 16; m <<= 1) {
            s0 += __shfl_xor(s0, m);
            s1 += __shfl_xor(s1, m);
        }
        float s2 = __shfl_down(s0, 16);         // rows 4u+2 (gate g), from rg=2u+1
        float s3 = __shfl_down(s1, 16);         // rows 4u+3 (gate o)
        if (upd) {
            int xb = (t >> 6) & 1, tt = t & 63;
            float gi = s0 + b2f(xst[xb][(0 * 8 + u) * 72 + tt]);
            float gf = s1 + b2f(xst[xb][(1 * 8 + u) * 72 + tt]);
            float gg = s2 + b2f(xst[xb][(2 * 8 + u) * 72 + tt]);
            float go = s3 + b2f(xst[xb][(3 * 8 + u) * 72 + tt]);
            float ii = sigm(gi), ff = sigm(gf), gv = tanh_(gg), oo = sigm(go);
            cj = ff * cj + ii * gv;
            float hnew = oo * tanh_(cj);
            __hip_atomic_store(&hsd[(size_t)t * HD + jbase + u], hnew,
                               __ATOMIC_RELAXED, __HIP_MEMORY_SCOPE_AGENT);
        }
        if (t < S - 1) {
            // value-canary poll (agent loads, proven-fresh): lane covers u64 slot tid
            const unsigned long long* pb =
                (const unsigned long long*)&hsd[(size_t)t * HD] + tid;
            unsigned long long v;
            for (;;) {
                v = __hip_atomic_load(pb, __ATOMIC_RELAXED, __HIP_MEMORY_SCOPE_AGENT);
                if ((uint_t)v != 0xFFFFFFFFu && (uint_t)(v >> 32) != 0xFFFFFFFFu) break;
            }
            int p = 2 * tid;
            *(unsigned long long*)&hstage[t & 1][(p >> 5) * 36 + (p & 31)] = v;
        }
        __syncthreads();                        // single barrier per step
    }
}

// ---------------- feats: [S][12] = concat(hf, hb_rev) @ w_out.T + b_out ----------------
__global__ __launch_bounds__(256)
void feats_k(const float* __restrict__ hs, const float* __restrict__ w_out,
             const float* __restrict__ b_out, float* __restrict__ feats) {
    const int t = blockIdx.x, tid = threadIdx.x;
    float4 h4;
    if (tid < 128)
        h4 = *(const float4*)&hs[(size_t)t * HD + tid * 4];
    else
        h4 = *(const float4*)&hs[(size_t)S * HD + (size_t)(S - 1 - t) * HD + (tid - 128) * 4];
    float acc[NT];
#pragma unroll
    for (int tg = 0; tg < NT; ++tg) {
        float4 w4 = *(const float4*)&w_out[(size_t)tg * 1024 + tid * 4];
        acc[tg] = h4.x * w4.x + h4.y * w4.y + h4.z * w4.z + h4.w * w4.w;
    }
#pragma unroll
    for (int m = 1; m < 64; m <<= 1)
#pragma unroll
        for (int tg = 0; tg < NT; ++tg) acc[tg] += __shfl_xor(acc[tg], m);
    __shared__ float part[4][NT];
    if ((tid & 63) == 0) {
#pragma unroll
        for (int tg = 0; tg < NT; ++tg) part[tid >> 6][tg] = acc[tg];
    }
    __syncthreads();
    if (tid < NT)
        feats[(size_t)t * NT + tid] =
            part[0][tid] + part[1][tid] + part[2][tid] + part[3][tid] + b_out[tid];
}

// ---------------- CRF: single wave, barrier-free forward, feats LDS-resident ------------
__global__ __launch_bounds__(64, 1)
void crf_k(const float* __restrict__ feats, const int* __restrict__ gold,
           const float* __restrict__ trans, float* __restrict__ out) {
    extern __shared__ float sf[];                 // S*NT = 24576 floats = 96 KB
    const int lane = threadIdx.x;
    for (int i = lane; i < S * NT / 4; i += 64)
        ((float4*)sf)[i] = ((const float4*)feats)[i];
    float Trow[NT];
#pragma unroll
    for (int j = 0; j < NT; ++j) Trow[j] = (lane < NT) ? trans[lane * NT + j] : 0.f;
    __syncthreads();
    // gold score (lane-strided partials, butterfly sum)
    float gsum = 0.f;
    for (int t = lane; t < S; t += 64) {
        int a = gold[t];
        int b = t ? gold[t - 1] : 0;              // tags[0] = START = 0
        gsum += trans[a * NT + b] + sf[t * NT + a];
    }
#pragma unroll
    for (int m = 1; m < 64; m <<= 1) gsum += __shfl_xor(gsum, m);
    // forward algorithm: alpha_j in lane j
    float alpha = (lane == 0) ? 0.f : -1e6f;
    const int femit = (lane < NT) ? lane : 0;
    for (int t = 0; t < S; ++t) {
        float aj[NT];
#pragma unroll
        for (int j = 0; j < NT; ++j) aj[j] = __shfl(alpha, j);
        float amax = aj[0];
#pragma unroll
        for (int j = 1; j < NT; ++j) amax = fmaxf(amax, aj[j]);
        float s = 0.f;
#pragma unroll
        for (int j = 0; j < NT; ++j) s += __expf(aj[j] - amax + Trow[j]);
        float anew = amax + __logf(s) + sf[t * NT + femit];
        alpha = (lane < NT) ? anew : -1e6f;
    }
    float v = (lane < NT) ? alpha + trans[1 * NT + lane] : -3e38f;
    float m2 = v;
#pragma unroll
    for (int mm = 1; mm < 16; mm <<= 1) m2 = fmaxf(m2, __shfl_xor(m2, mm));
    float ss = __expf(v - m2);
#pragma unroll
    for (int mm = 1; mm < 16; mm <<= 1) ss += __shfl_xor(ss, mm);
    if (lane == 0)
        out[0] = (m2 + __logf(ss)) - (gsum + trans[1 * NT + gold[S - 1]]);
}

extern "C" void kernel_launch(void* const* d_in, const int* in_sizes, int n_in,
                              void* d_out, int out_size, void* d_ws, size_t ws_size,
                              hipStream_t stream) {
    const int* sentence = (const int*)d_in[0];
    const int* gold = (const int*)d_in[1];
    const float* emb = (const float*)d_in[2];
    const float* wih_f = (const float*)d_in[3];
    const float* whh_f = (const float*)d_in[4];
    const float* b_f = (const float*)d_in[5];
    const float* wih_b = (const float*)d_in[6];
    const float* whh_b = (const float*)d_in[7];
    const float* b_b = (const float*)d_in[8];
    const float* w_out = (const float*)d_in[9];
    const float* b_out = (const float*)d_in[10];
    const float* trans = (const float*)d_in[11];
    const float* h0 = (const float*)d_in[12];
    const float* c0 = (const float*)d_in[13];
    float* out = (float*)d_out;

    char* ws = (char*)d_ws;
    const size_t XW_B = (size_t)2 * S * G4 * 2;          // 16,777,216
    const size_t HS_B = (size_t)2 * S * HD * 4;          // 8,388,608
    ushort_t* xwT = (ushort_t*)ws;
    float* hs = (float*)(ws + XW_B);
    float* feats = (float*)(ws + XW_B + HS_B);

    // canary-fill h state buffer (0xFFFFFFFF, impossible output value)
    hipMemsetAsync(hs, 0xFF, HS_B, stream);

    dim3 gg(S / 64, G4 / 64, 2);
    xw_gemm<<<gg, 256, 0, stream>>>(sentence, emb, wih_f, b_f, wih_b, b_b, xwT);

    lstm_rec<<<2 * NWGD, 256, 0, stream>>>(whh_f, whh_b, h0, c0, xwT, hs);

    feats_k<<<S, 256, 0, stream>>>(hs, w_out, b_out, feats);

    const int CRF_LDS = S * NT * 4;                      // 98,304 B
    hipFuncSetAttribute((const void*)crf_k,
                        hipFuncAttributeMaxDynamicSharedMemorySize, CRF_LDS);
    crf_k<<<1, 64, CRF_LDS, stream>>>(feats, gold, trans, out);
}